// Round 2
// baseline (18411.557 us; speedup 1.0000x reference)
//
#include <hip/hip_runtime.h>
#include <hip/hip_bf16.h>

typedef unsigned int uint32;
typedef unsigned short ushort16;

#define GBLK 256
#define BT 256
#define NSTEP 128

struct Params {
  const int* inputs;
  const void *h1_in, *h2_in, *pk, *enc, *embeds, *Wq, *vatt;
  const void *Wih1, *Whh1, *bih1, *bhh1;
  const void *Wih2, *Whh2, *bih2, *bhh2;
  const void *Wpre, *bpre, *Wout, *bout;
  void* out;
  float* ws;
  int* bar;
};

__device__ __forceinline__ float bfs(ushort16 u) { return __uint_as_float(((uint32)u) << 16); }
__device__ __forceinline__ float blo(uint32 u) { return __uint_as_float(u << 16); }
__device__ __forceinline__ float bhi(uint32 u) { return __uint_as_float(u & 0xffff0000u); }

template <bool BF>
__device__ __forceinline__ float ld1(const void* p, size_t i) {
  if constexpr (BF) return bfs(((const ushort16*)p)[i]);
  else return ((const float*)p)[i];
}
template <bool BF>
__device__ __forceinline__ void st1(void* p, size_t i, float v) {
  if constexpr (BF) ((__hip_bfloat16*)p)[i] = __float2bfloat16(v);
  else ((float*)p)[i] = v;
}
template <bool BF>
__device__ __forceinline__ const void* eptr(const void* p, size_t off) {
  if constexpr (BF) return (const void*)((const ushort16*)p + off);
  else return (const void*)((const float*)p + off);
}

__device__ __forceinline__ float wsum(float v) {
#pragma unroll
  for (int o = 32; o; o >>= 1) v += __shfl_xor(v, o, 64);
  return v;
}

// dot of W-row segment (dtype) with f32 x segment; partial per lane (reduce with wsum)
template <bool BF, int K>
__device__ __forceinline__ float dotW_f(const void* Wv, const float* __restrict__ x, int lane) {
  float s = 0.f;
  if constexpr (BF) {
    const ushort16* Wr = (const ushort16*)Wv;
#pragma unroll
    for (int k0 = 0; k0 < K; k0 += 512) {
      int k = k0 + lane * 8;
      uint4 w = *(const uint4*)(Wr + k);
      float4 x0 = *(const float4*)(x + k);
      float4 x1 = *(const float4*)(x + k + 4);
      s += blo(w.x) * x0.x + bhi(w.x) * x0.y + blo(w.y) * x0.z + bhi(w.y) * x0.w +
           blo(w.z) * x1.x + bhi(w.z) * x1.y + blo(w.w) * x1.z + bhi(w.w) * x1.w;
    }
  } else {
    const float* Wr = (const float*)Wv;
#pragma unroll
    for (int k0 = 0; k0 < K; k0 += 512) {
      int k = k0 + lane * 8;
      float4 w0 = *(const float4*)(Wr + k);
      float4 w1 = *(const float4*)(Wr + k + 4);
      float4 x0 = *(const float4*)(x + k);
      float4 x1 = *(const float4*)(x + k + 4);
      s += w0.x * x0.x + w0.y * x0.y + w0.z * x0.z + w0.w * x0.w +
           w1.x * x1.x + w1.y * x1.y + w1.z * x1.z + w1.w * x1.w;
    }
  }
  return s;
}

// dot of W-row segment (dtype) with x segment (dtype)
template <bool BF, int K>
__device__ __forceinline__ float dotW_t(const void* Wv, const void* Xv, int lane) {
  if constexpr (BF) {
    const ushort16* Wr = (const ushort16*)Wv;
    const ushort16* Xr = (const ushort16*)Xv;
    float s = 0.f;
#pragma unroll
    for (int k0 = 0; k0 < K; k0 += 512) {
      int k = k0 + lane * 8;
      uint4 w = *(const uint4*)(Wr + k);
      uint4 xv = *(const uint4*)(Xr + k);
      s += blo(w.x) * blo(xv.x) + bhi(w.x) * bhi(xv.x) + blo(w.y) * blo(xv.y) +
           bhi(w.y) * bhi(xv.y) + blo(w.z) * blo(xv.z) + bhi(w.z) * bhi(xv.z) +
           blo(w.w) * blo(xv.w) + bhi(w.w) * bhi(xv.w);
    }
    return s;
  } else {
    return dotW_f<false, K>(Wv, (const float*)Xv, lane);
  }
}

// two-level monotonic grid barrier: 8 group counters (32 blocks each) -> root -> release
__device__ __forceinline__ void gbar(int* bar, int k) {
  __threadfence();
  __syncthreads();
  if (threadIdx.x == 0) {
    const int grp = blockIdx.x & 7;
    int v = __hip_atomic_fetch_add(&bar[grp * 64], 1, __ATOMIC_ACQ_REL, __HIP_MEMORY_SCOPE_AGENT);
    if (v == k * 32 - 1) {
      int r = __hip_atomic_fetch_add(&bar[512], 1, __ATOMIC_ACQ_REL, __HIP_MEMORY_SCOPE_AGENT);
      if (r == k * 8 - 1)
        __hip_atomic_store(&bar[576], k, __ATOMIC_RELEASE, __HIP_MEMORY_SCOPE_AGENT);
    }
    while (__hip_atomic_load(&bar[576], __ATOMIC_RELAXED, __HIP_MEMORY_SCOPE_AGENT) < k) {
      __builtin_amdgcn_s_sleep(1);
    }
    (void)__hip_atomic_load(&bar[576], __ATOMIC_ACQUIRE, __HIP_MEMORY_SCOPE_AGENT);
  }
  __syncthreads();
}

__device__ __forceinline__ float sigm(float x) { return 1.f / (1.f + expf(-x)); }
__device__ __forceinline__ float lrelu(float x) { return x >= 0.f ? x : 0.01f * x; }

template <bool BF>
__device__ void run_decoder(const Params& p, float* s_red, float* s_ctx) {
  const int tid = threadIdx.x;
  const int lane = tid & 63;
  const int wid = tid >> 6;
  const int gw = blockIdx.x * 4 + wid;  // 0..1023

  float* h1 = p.ws + 1024;
  float* h2 = p.ws + 2048;
  float* q = p.ws + 3072;
  float* ev = p.ws + 4096;   // 256
  float* ctx = p.ws + 4352;  // 2048
  float* o1 = p.ws + 6400;
  float* o2 = p.ws + 7424;
  float* gh1 = p.ws + 8448;   // 3072
  float* gh2 = p.ws + 11520;  // 3072

  void* out = p.out;
  const size_t off_outs = 0;        // 128*512
  const size_t off_pres = 65536;    // 128*1024
  const size_t off_alph = 196608;   // 128*256
  const size_t off_h1f = 229376;
  const size_t off_h2f = 230400;

  // init recurrent state (f32)
  if (gw < 16) h1[gw * 64 + lane] = ld1<BF>(p.h1_in, gw * 64 + lane);
  else if (gw < 32) h2[(gw - 16) * 64 + lane] = ld1<BF>(p.h2_in, (gw - 16) * 64 + lane);

  int bk = 0;
  for (int t = 0; t < NSTEP; ++t) {
    gbar(p.bar, ++bk);
    // ---------- Phase A: epilogue(t-1) + q + gh1 + gh2 ----------
    if (t > 0) {
      const void* embp = eptr<BF>(p.embeds, (size_t)p.inputs[t - 1] * 512);
      {  // pre row gw  (K = 512 emb | 1024 o2 | 2048 ctx)
        const void* wr = eptr<BF>(p.Wpre, (size_t)gw * 3584);
        float s = dotW_t<BF, 512>(wr, embp, lane) +
                  dotW_f<BF, 1024>(eptr<BF>(wr, 512), o2, lane) +
                  dotW_f<BF, 2048>(eptr<BF>(wr, 1536), ctx, lane);
        s = wsum(s);
        if (lane == 0) {
          s += ld1<BF>(p.bpre, gw);
          st1<BF>(out, off_pres + (size_t)(t - 1) * 1024 + gw, lrelu(s));
        }
      }
      if (gw < 512) {  // out row gw
        const void* wr = eptr<BF>(p.Wout, (size_t)gw * 1024);
        float s = wsum(dotW_f<BF, 1024>(wr, o2, lane));
        if (lane == 0)
          st1<BF>(out, off_outs + (size_t)(t - 1) * 512 + gw, s + ld1<BF>(p.bout, gw));
      }
    }
    {  // q row gw
      float s = wsum(dotW_f<BF, 1024>(eptr<BF>(p.Wq, (size_t)gw * 1024), h2, lane));
      if (lane == 0) q[gw] = s;
    }
#pragma unroll
    for (int j = 0; j < 3; ++j) {  // gh1/gh2 rows j*1024+gw
      int r = j * 1024 + gw;
      float s1 = wsum(dotW_f<BF, 1024>(eptr<BF>(p.Whh1, (size_t)r * 1024), h1, lane));
      if (lane == 0) gh1[r] = s1 + ld1<BF>(p.bhh1, r);
      float s2 = wsum(dotW_f<BF, 1024>(eptr<BF>(p.Whh2, (size_t)r * 1024), h2, lane));
      if (lane == 0) gh2[r] = s2 + ld1<BF>(p.bhh2, r);
    }
    gbar(p.bar, ++bk);
    // ---------- Phase B: e[b] = tanh(pk[b,:]+q)·v ----------
    {
      const void* pkr = eptr<BF>(p.pk, (size_t)blockIdx.x * 1024);
      int kk = tid * 4;
      float s = 0.f;
#pragma unroll
      for (int j = 0; j < 4; ++j)
        s += tanhf(ld1<BF>(pkr, kk + j) + q[kk + j]) * ld1<BF>(p.vatt, kk + j);
      s = wsum(s);
      if (lane == 0) s_red[wid] = s;
      __syncthreads();
      if (tid == 0) ev[blockIdx.x] = s_red[0] + s_red[1] + s_red[2] + s_red[3];
    }
    gbar(p.bar, ++bk);
    // ---------- Phase C: softmax (redundant per block) + context slice ----------
    {
      float e_i = ev[tid];
      float mw = e_i;
#pragma unroll
      for (int o = 32; o; o >>= 1) mw = fmaxf(mw, __shfl_xor(mw, o, 64));
      if (lane == 0) s_red[wid] = mw;
      __syncthreads();
      float m = fmaxf(fmaxf(s_red[0], s_red[1]), fmaxf(s_red[2], s_red[3]));
      __syncthreads();
      float pexp = expf(e_i - m);
      float zw = wsum(pexp);
      if (lane == 0) s_red[wid] = zw;
      __syncthreads();
      float Z = s_red[0] + s_red[1] + s_red[2] + s_red[3];
      float alpha = pexp / Z;
      if (blockIdx.x == 0) st1<BF>(out, off_alph + (size_t)t * 256 + tid, alpha);
      // context: block owns 8 columns, thread owns encoder row tid
      int j0 = blockIdx.x * 8;
      const void* er = eptr<BF>(p.enc, (size_t)tid * 2048 + j0);
#pragma unroll
      for (int j = 0; j < 8; ++j) s_ctx[tid * 8 + j] = alpha * ld1<BF>(er, j);
      __syncthreads();
      for (int st = 128; st >= 1; st >>= 1) {
        if (tid < st) {
#pragma unroll
          for (int j = 0; j < 8; ++j) s_ctx[tid * 8 + j] += s_ctx[(tid + st) * 8 + j];
        }
        __syncthreads();
      }
      if (tid < 8) ctx[j0 + tid] = s_ctx[tid];
    }
    gbar(p.bar, ++bk);
    // ---------- Phase D: GRU1, wave owns h-index i=gw ----------
    {
      const void* embc = eptr<BF>(p.embeds, (size_t)p.inputs[t] * 512);
      const int i = gw;
      const void* wr = eptr<BF>(p.Wih1, (size_t)i * 2560);
      const void* wz = eptr<BF>(p.Wih1, (size_t)(1024 + i) * 2560);
      const void* wn = eptr<BF>(p.Wih1, (size_t)(2048 + i) * 2560);
      float sr = dotW_t<BF, 512>(wr, embc, lane) + dotW_f<BF, 2048>(eptr<BF>(wr, 512), ctx, lane);
      float sz = dotW_t<BF, 512>(wz, embc, lane) + dotW_f<BF, 2048>(eptr<BF>(wz, 512), ctx, lane);
      float sn = dotW_t<BF, 512>(wn, embc, lane) + dotW_f<BF, 2048>(eptr<BF>(wn, 512), ctx, lane);
      sr = wsum(sr); sz = wsum(sz); sn = wsum(sn);
      if (lane == 0) {
        float r = sigm(sr + ld1<BF>(p.bih1, i) + gh1[i]);
        float z = sigm(sz + ld1<BF>(p.bih1, 1024 + i) + gh1[1024 + i]);
        float n = tanhf(sn + ld1<BF>(p.bih1, 2048 + i) + r * gh1[2048 + i]);
        float h = (1.f - z) * n + z * h1[i];
        h1[i] = h;
        o1[i] = lrelu(h);
      }
    }
    gbar(p.bar, ++bk);
    // ---------- Phase E: GRU2, wave owns h-index i=gw ----------
    {
      const int i = gw;
      const void* wr = eptr<BF>(p.Wih2, (size_t)i * 3072);
      const void* wz = eptr<BF>(p.Wih2, (size_t)(1024 + i) * 3072);
      const void* wn = eptr<BF>(p.Wih2, (size_t)(2048 + i) * 3072);
      float sr = dotW_f<BF, 1024>(wr, o1, lane) + dotW_f<BF, 2048>(eptr<BF>(wr, 1024), ctx, lane);
      float sz = dotW_f<BF, 1024>(wz, o1, lane) + dotW_f<BF, 2048>(eptr<BF>(wz, 1024), ctx, lane);
      float sn = dotW_f<BF, 1024>(wn, o1, lane) + dotW_f<BF, 2048>(eptr<BF>(wn, 1024), ctx, lane);
      sr = wsum(sr); sz = wsum(sz); sn = wsum(sn);
      if (lane == 0) {
        float r = sigm(sr + ld1<BF>(p.bih2, i) + gh2[i]);
        float z = sigm(sz + ld1<BF>(p.bih2, 1024 + i) + gh2[1024 + i]);
        float n = tanhf(sn + ld1<BF>(p.bih2, 2048 + i) + r * gh2[2048 + i]);
        float h = (1.f - z) * n + z * h2[i];
        h2[i] = h;
        o2[i] = lrelu(h);
      }
    }
  }
  gbar(p.bar, ++bk);
  // ---------- Final: epilogue for t=127 + final states ----------
  {
    const void* embp = eptr<BF>(p.embeds, (size_t)p.inputs[NSTEP - 1] * 512);
    {
      const void* wr = eptr<BF>(p.Wpre, (size_t)gw * 3584);
      float s = dotW_t<BF, 512>(wr, embp, lane) +
                dotW_f<BF, 1024>(eptr<BF>(wr, 512), o2, lane) +
                dotW_f<BF, 2048>(eptr<BF>(wr, 1536), ctx, lane);
      s = wsum(s);
      if (lane == 0) {
        s += ld1<BF>(p.bpre, gw);
        st1<BF>(out, off_pres + (size_t)(NSTEP - 1) * 1024 + gw, lrelu(s));
      }
    }
    if (gw < 512) {
      const void* wr = eptr<BF>(p.Wout, (size_t)gw * 1024);
      float s = wsum(dotW_f<BF, 1024>(wr, o2, lane));
      if (lane == 0)
        st1<BF>(out, off_outs + (size_t)(NSTEP - 1) * 512 + gw, s + ld1<BF>(p.bout, gw));
    }
    if (gw < 16) st1<BF>(out, off_h1f + gw * 64 + lane, h1[gw * 64 + lane]);
    else if (gw < 32) st1<BF>(out, off_h2f + (gw - 16) * 64 + lane, h2[(gw - 16) * 64 + lane]);
  }
}

__global__ __launch_bounds__(BT, 1) void dec_SAVE_30683246363209_kernel(Params p) {
  // Device-side dtype probe: h1 ~ N(0,1). If the buffer is packed bf16, every
  // 16-bit half has a sane bf16 exponent field; if fp32, low halves are random
  // mantissa bits (~16% hit rate). 128 halves: bf16 -> ~128 hits, fp32 -> ~74.
  const uint32* hw = (const uint32*)p.h1_in;
  int hits = 0;
#pragma unroll
  for (int i = 0; i < 64; ++i) {
    uint32 w = hw[i];
    int e0 = (int)((w >> 7) & 0xff);
    int e1 = (int)((w >> 23) & 0xff);
    hits += (e0 >= 100 && e0 <= 140) ? 1 : 0;
    hits += (e1 >= 100 && e1 <= 140) ? 1 : 0;
  }
  __shared__ float s_red[4];
  __shared__ float s_ctx[256 * 8];
  if (hits >= 104) run_decoder<true>(p, s_red, s_ctx);
  else run_decoder<false>(p, s_red, s_ctx);
}

extern "C" void kernel_launch(void* const* d_in, const int* in_sizes, int n_in,
                              void* d_out, int out_size, void* d_ws, size_t ws_size,
                              hipStream_t stream) {
  // zero barrier counters + shared state region (ws is poisoned 0xAA before every launch)
  hipMemsetAsync(d_ws, 0, 65536, stream);

  Params p;
  p.inputs = (const int*)d_in[0];
  p.h1_in = d_in[1];
  p.h2_in = d_in[2];
  p.pk = d_in[3];
  p.enc = d_in[4];
  p.embeds = d_in[5];
  p.Wq = d_in[6];
  p.vatt = d_in[7];
  p.Wih1 = d_in[8];
  p.Whh1 = d_in[9];
  p.bih1 = d_in[10];
  p.bhh1 = d_in[11];
  p.Wih2 = d_in[12];
  p.Whh2 = d_in[13];
  p.bih2 = d_in[14];
  p.bhh2 = d_in[15];
  p.Wpre = d_in[16];
  p.bpre = d_in[17];
  p.Wout = d_in[18];
  p.bout = d_in[19];
  p.out = d_out;
  p.ws = (float*)d_ws;
  p.bar = (int*)d_ws;

  void* args[] = {&p};
  hipLaunchCooperativeKernel((const void*)dec_SAVE_30683246363209_kernel, dim3(GBLK),
                             dim3(BT), args, 0, stream);
}